// Round 1
// baseline (57.838 us; speedup 1.0000x reference)
//
#include <hip/hip_runtime.h>
#include <hip/hip_bf16.h>

#define B_ 4
#define N_ 20000
#define D_ 128
#define E_ 100000

typedef __attribute__((ext_vector_type(8))) short bf16x8;
typedef __attribute__((ext_vector_type(4))) float f32x4;

// ws layout (float units):
// [0,512)        g accumulator (B x D)
// [512,516)      qg (B)
// [516]          flag (int: 1 = edges are int64, 0 = int32)
// [1024,9216)    w7t: bf16[128][128] (W7 transposed, col-major for B-frags)
// [9216,89216)   qi (B x N)
// [89216,169216) qj (B x N)

__global__ void k_w7t(const float* __restrict__ W7, __hip_bfloat16* __restrict__ w7t) {
    int idx = blockIdx.x * 256 + threadIdx.x;   // 0..16383
    int k = idx >> 7, e = idx & 127;
    w7t[e * 128 + k] = __float2bfloat16(W7[idx]);
}

__global__ void k_detect(const unsigned* __restrict__ ew, int* __restrict__ flag) {
    int t = threadIdx.x;
    unsigned v = ew[2 * t + 1];   // high words if int64 (all zero), v-values if int32
    unsigned long long any = __ballot(v != 0u);
    if (t == 0) *flag = (any == 0ULL) ? 1 : 0;
}

__global__ __launch_bounds__(256) void k_main(
    const float* __restrict__ emb, const __hip_bfloat16* __restrict__ w7t,
    const float* __restrict__ w5, float* __restrict__ g,
    float* __restrict__ qi, float* __restrict__ qj)
{
    __shared__ __hip_bfloat16 sA[64][136];   // emb tile (nodes x k), pad->272B stride
    __shared__ __hip_bfloat16 sB[128][136];  // W7^T (cols x k)
    __shared__ float sred[4][128];           // g partial reduction

    const int t  = threadIdx.x;
    const int b  = blockIdx.y;
    const int n0 = blockIdx.x * 64;

    // ---- stage A tile (fp32 -> bf16) + g column partials from same registers
    {
        const int c2 = t & 63;   // float2 column index (covers 128 cols)
        const int r0 = t >> 6;   // 0..3
        float gp0 = 0.f, gp1 = 0.f;
        #pragma unroll
        for (int i = 0; i < 16; ++i) {
            int r = r0 + 4 * i;
            int n = n0 + r;
            float2 v = make_float2(0.f, 0.f);
            if (n < N_) v = ((const float2*)(emb + ((size_t)b * N_ + n) * D_))[c2];
            gp0 += v.x; gp1 += v.y;
            __hip_bfloat162 h2;
            h2.x = __float2bfloat16(v.x);
            h2.y = __float2bfloat16(v.y);
            *reinterpret_cast<__hip_bfloat162*>(&sA[r][2 * c2]) = h2;
        }
        sred[r0][2 * c2]     = gp0;
        sred[r0][2 * c2 + 1] = gp1;
    }
    // ---- stage B (w7t bf16, 8192 dwords, coalesced, conflict-free writes)
    {
        const unsigned* w32 = (const unsigned*)w7t;
        #pragma unroll
        for (int i = 0; i < 32; ++i) {
            int idx = t + 256 * i;      // 0..8191
            int e  = idx >> 6;          // row (output col), 64 dwords per row
            int kp = idx & 63;
            *reinterpret_cast<unsigned*>(&sB[e][2 * kp]) = w32[idx];
        }
    }
    __syncthreads();

    // ---- g reduction: 4 partial rows -> one atomic per column per block
    if (t < 128) {
        float s = sred[0][t] + sred[1][t] + sred[2][t] + sred[3][t];
        atomicAdd(&g[b * D_ + t], s);
    }

    // ---- MFMA: each wave does 16 nodes x 128 cols, K=128
    const int lane = t & 63;
    const int wv   = t >> 6;       // wave: node sub-tile
    const int rc   = lane & 15;    // A row / B col within tile
    const int kg   = lane >> 4;    // k group 0..3

    f32x4 acc[8] = {};
    #pragma unroll
    for (int s = 0; s < 4; ++s) {
        const int koff = s * 32 + kg * 8;
        bf16x8 a = *(const bf16x8*)&sA[wv * 16 + rc][koff];
        #pragma unroll
        for (int tt = 0; tt < 8; ++tt) {
            bf16x8 bf = *(const bf16x8*)&sB[tt * 16 + rc][koff];
            acc[tt] = __builtin_amdgcn_mfma_f32_16x16x32_bf16(a, bf, acc[tt], 0, 0, 0);
        }
    }

    // ---- epilogue: leaky_relu, weight by w5_i/w5_j, reduce over 128 cols
    // D layout: col = lane&15 (=rc), row = kg*4 + reg
    float qip[4] = {0, 0, 0, 0}, qjp[4] = {0, 0, 0, 0};
    #pragma unroll
    for (int tt = 0; tt < 8; ++tt) {
        int col = tt * 16 + rc;
        float wi = w5[D_ + col];
        float wj = w5[2 * D_ + col];
        #pragma unroll
        for (int r = 0; r < 4; ++r) {
            float p  = acc[tt][r];
            float lr = (p >= 0.f) ? p : 0.01f * p;
            qip[r] += lr * wi;
            qjp[r] += lr * wj;
        }
    }
    #pragma unroll
    for (int m = 1; m < 16; m <<= 1) {
        #pragma unroll
        for (int r = 0; r < 4; ++r) {
            qip[r] += __shfl_xor(qip[r], m);
            qjp[r] += __shfl_xor(qjp[r], m);
        }
    }
    if (rc == 0) {
        #pragma unroll
        for (int r = 0; r < 4; ++r) {
            int node = n0 + wv * 16 + kg * 4 + r;
            if (node < N_) {
                qi[b * N_ + node] = qip[r];
                qj[b * N_ + node] = qjp[r];
            }
        }
    }
}

__global__ __launch_bounds__(128) void k_qg(
    const float* __restrict__ g, const float* __restrict__ W6,
    const float* __restrict__ w5, const float* __restrict__ wno,
    float* __restrict__ qg, float* __restrict__ out)
{
    __shared__ float sg[128];
    __shared__ float sr[2], sr2[2];
    const int b = blockIdx.x;
    const int e = threadIdx.x;
    sg[e] = g[b * D_ + e];
    __syncthreads();
    float p = 0.f;
    #pragma unroll 8
    for (int d = 0; d < 128; ++d)
        p += sg[d] * W6[d * D_ + e];
    float lr = (p >= 0.f) ? p : 0.01f * p;
    float vq = lr * w5[e];          // w5_g
    float vn = sg[e] * wno[e];      // noop
    #pragma unroll
    for (int m = 1; m < 64; m <<= 1) {
        vq += __shfl_xor(vq, m);
        vn += __shfl_xor(vn, m);
    }
    if ((e & 63) == 0) { sr[e >> 6] = vq; sr2[e >> 6] = vn; }
    __syncthreads();
    if (e == 0) {
        qg[b] = sr[0] + sr[1];
        out[(size_t)b * (E_ + 1) + E_] = sr2[0] + sr2[1];
    }
}

__global__ __launch_bounds__(256) void k_edge(
    const int* __restrict__ edges, const int* __restrict__ flag,
    const float* __restrict__ qg, const float* __restrict__ qi,
    const float* __restrict__ qj, float* __restrict__ out)
{
    int e = blockIdx.x * 256 + threadIdx.x;
    if (e >= E_) return;
    int is64 = *flag;
    int u, v;
    if (is64) { u = edges[4 * e]; v = edges[4 * e + 2]; }
    else      { u = edges[2 * e]; v = edges[2 * e + 1]; }
    float q0 = qg[0], q1 = qg[1], q2 = qg[2], q3 = qg[3];
    out[0 * (size_t)(E_ + 1) + e] = q0 + qi[0 * N_ + u] + qj[0 * N_ + v];
    out[1 * (size_t)(E_ + 1) + e] = q1 + qi[1 * N_ + u] + qj[1 * N_ + v];
    out[2 * (size_t)(E_ + 1) + e] = q2 + qi[2 * N_ + u] + qj[2 * N_ + v];
    out[3 * (size_t)(E_ + 1) + e] = q3 + qi[3 * N_ + u] + qj[3 * N_ + v];
}

extern "C" void kernel_launch(void* const* d_in, const int* in_sizes, int n_in,
                              void* d_out, int out_size, void* d_ws, size_t ws_size,
                              hipStream_t stream)
{
    const float* emb   = (const float*)d_in[0];
    const int*   edges = (const int*)d_in[1];
    const float* W6    = (const float*)d_in[2];
    const float* W7    = (const float*)d_in[3];
    const float* w5    = (const float*)d_in[4];
    const float* wno   = (const float*)d_in[5];
    float* out = (float*)d_out;

    float* W = (float*)d_ws;
    float* g    = W;
    float* qg   = W + 512;
    int*   flag = (int*)(W + 516);
    __hip_bfloat16* w7t = (__hip_bfloat16*)(W + 1024);
    float* qi = W + 9216;
    float* qj = W + 89216;

    hipMemsetAsync(g, 0, 512 * sizeof(float), stream);
    hipLaunchKernelGGL(k_w7t, dim3(64), dim3(256), 0, stream, W7, w7t);
    hipLaunchKernelGGL(k_detect, dim3(1), dim3(64), 0, stream,
                       (const unsigned*)edges, flag);
    hipLaunchKernelGGL(k_main, dim3((N_ + 63) / 64, B_), dim3(256), 0, stream,
                       emb, w7t, w5, g, qi, qj);
    hipLaunchKernelGGL(k_qg, dim3(B_), dim3(128), 0, stream, g, W6, w5, wno, qg, out);
    hipLaunchKernelGGL(k_edge, dim3((E_ + 255) / 256), dim3(256), 0, stream,
                       edges, flag, qg, qi, qj, out);
}

// Round 2
// 44.586 us; speedup vs baseline: 1.2972x; 1.2972x over previous
//
#include <hip/hip_runtime.h>
#include <hip/hip_bf16.h>

#define B_ 4
#define N_ 20000
#define D_ 128
#define E_ 100000

typedef __attribute__((ext_vector_type(8))) short bf16x8;
typedef __attribute__((ext_vector_type(4))) float f32x4;

// ws layout (float units):
// [0,512)        g accumulator (B x D)
// [512,516)      qg (B)
// [516]          flag (int: 1 = edges are int64, 0 = int32)
// [1024,9216)    w7t: bf16[128][128] (W7 transposed)
// [9216,89216)   qi (B x N)
// [89216,169216) qj (B x N)

// blocks 0..63: W7 -> w7t (transposed, bf16). block 64: int64 detection.
__global__ void k_prep(const float* __restrict__ W7, __hip_bfloat16* __restrict__ w7t,
                       const unsigned* __restrict__ ew, int* __restrict__ flag) {
    if (blockIdx.x == 64) {
        if (threadIdx.x < 64) {
            unsigned v = ew[2 * threadIdx.x + 1]; // high words if int64 (all zero)
            unsigned long long any = __ballot(v != 0u);
            if (threadIdx.x == 0) *flag = (any == 0ULL) ? 1 : 0;
        }
        return;
    }
    int idx = blockIdx.x * 256 + threadIdx.x;   // 0..16383
    int k = idx >> 7, e = idx & 127;
    w7t[e * 128 + k] = __float2bfloat16(W7[idx]);
}

__global__ __launch_bounds__(256, 2) void k_main(
    const float* __restrict__ emb, const __hip_bfloat16* __restrict__ w7t,
    const float* __restrict__ w5, float* __restrict__ g,
    float* __restrict__ qi, float* __restrict__ qj)
{
    __shared__ __hip_bfloat16 sA[128][136];  // node tile (rows x k), 272B stride
    __shared__ __hip_bfloat16 sB[128][136];  // W7^T (out-col x k)
    __shared__ float sred[8][128];           // g partials

    const int t  = threadIdx.x;
    const int b  = blockIdx.y;
    const int n0 = blockIdx.x * 128;

    // ---- stage A (float4 loads, fp32->bf16) + g column partials
    {
        const int c4 = t & 31;   // float4 column (32 per row)
        const int r0 = t >> 5;   // 0..7
        float gp0 = 0.f, gp1 = 0.f, gp2 = 0.f, gp3 = 0.f;
        #pragma unroll
        for (int i = 0; i < 16; ++i) {
            int r = r0 + 8 * i;
            int n = n0 + r;
            float4 v = make_float4(0.f, 0.f, 0.f, 0.f);
            if (n < N_) v = ((const float4*)(emb + ((size_t)b * N_ + n) * D_))[c4];
            gp0 += v.x; gp1 += v.y; gp2 += v.z; gp3 += v.w;
            union { short4 s4; __hip_bfloat16 h[4]; } pk;
            pk.h[0] = __float2bfloat16(v.x);
            pk.h[1] = __float2bfloat16(v.y);
            pk.h[2] = __float2bfloat16(v.z);
            pk.h[3] = __float2bfloat16(v.w);
            *reinterpret_cast<short4*>(&sA[r][4 * c4]) = pk.s4;
        }
        sred[r0][4 * c4]     = gp0;
        sred[r0][4 * c4 + 1] = gp1;
        sred[r0][4 * c4 + 2] = gp2;
        sred[r0][4 * c4 + 3] = gp3;
    }
    // ---- stage B with uint4 (2048 uint4 total, 8 per thread)
    {
        const uint4* w128 = (const uint4*)w7t;
        #pragma unroll
        for (int it = 0; it < 8; ++it) {
            int d4 = it * 256 + t;          // 0..2047
            int e   = d4 >> 4;              // row (16 uint4 per 128-bf16 row)
            int kp4 = d4 & 15;
            *reinterpret_cast<uint4*>(&sB[e][8 * kp4]) = w128[d4];
        }
    }
    __syncthreads();

    // ---- g reduction: one atomic per column per block
    if (t < 128) {
        float s = 0.f;
        #pragma unroll
        for (int r = 0; r < 8; ++r) s += sred[r][t];
        atomicAdd(&g[b * D_ + t], s);
    }

    // ---- MFMA: wave wv covers rows [wv*32, wv*32+32), all 128 cols, K=128
    const int lane = t & 63;
    const int wv   = t >> 6;
    const int rc   = lane & 15;
    const int kg   = lane >> 4;

    f32x4 acc[2][8] = {};
    #pragma unroll
    for (int s = 0; s < 4; ++s) {
        const int koff = s * 32 + kg * 8;
        bf16x8 bfr[8];
        #pragma unroll
        for (int tt = 0; tt < 8; ++tt)
            bfr[tt] = *(const bf16x8*)&sB[tt * 16 + rc][koff];
        #pragma unroll
        for (int rt = 0; rt < 2; ++rt) {
            bf16x8 a = *(const bf16x8*)&sA[wv * 32 + rt * 16 + rc][koff];
            #pragma unroll
            for (int tt = 0; tt < 8; ++tt)
                acc[rt][tt] = __builtin_amdgcn_mfma_f32_16x16x32_bf16(a, bfr[tt], acc[rt][tt], 0, 0, 0);
        }
    }

    // ---- epilogue: leaky, dot with w5_i / w5_j, reduce over cols, store
    // D layout: col = rc (lane&15), row = kg*4 + reg
    #pragma unroll
    for (int rt = 0; rt < 2; ++rt) {
        float qip[4] = {0, 0, 0, 0}, qjp[4] = {0, 0, 0, 0};
        #pragma unroll
        for (int tt = 0; tt < 8; ++tt) {
            int col = tt * 16 + rc;
            float wi = w5[D_ + col];
            float wj = w5[2 * D_ + col];
            #pragma unroll
            for (int r = 0; r < 4; ++r) {
                float p  = acc[rt][tt][r];
                float lr = (p >= 0.f) ? p : 0.01f * p;
                qip[r] += lr * wi;
                qjp[r] += lr * wj;
            }
        }
        #pragma unroll
        for (int m = 1; m < 16; m <<= 1) {
            #pragma unroll
            for (int r = 0; r < 4; ++r) {
                qip[r] += __shfl_xor(qip[r], m);
                qjp[r] += __shfl_xor(qjp[r], m);
            }
        }
        if (rc == 0) {
            #pragma unroll
            for (int r = 0; r < 4; ++r) {
                int node = n0 + wv * 32 + rt * 16 + kg * 4 + r;
                if (node < N_) {
                    qi[b * N_ + node] = qip[r];
                    qj[b * N_ + node] = qjp[r];
                }
            }
        }
    }
}

__global__ __launch_bounds__(128) void k_qg(
    const float* __restrict__ g, const float* __restrict__ W6,
    const float* __restrict__ w5, const float* __restrict__ wno,
    float* __restrict__ qg, float* __restrict__ out)
{
    __shared__ float sg[128];
    __shared__ float sr[2], sr2[2];
    const int b = blockIdx.x;
    const int e = threadIdx.x;
    sg[e] = g[b * D_ + e];
    __syncthreads();
    float p = 0.f;
    #pragma unroll 8
    for (int d = 0; d < 128; ++d)
        p += sg[d] * W6[d * D_ + e];
    float lr = (p >= 0.f) ? p : 0.01f * p;
    float vq = lr * w5[e];          // w5_g
    float vn = sg[e] * wno[e];      // noop
    #pragma unroll
    for (int m = 1; m < 64; m <<= 1) {
        vq += __shfl_xor(vq, m);
        vn += __shfl_xor(vn, m);
    }
    if ((e & 63) == 0) { sr[e >> 6] = vq; sr2[e >> 6] = vn; }
    __syncthreads();
    if (e == 0) {
        qg[b] = sr[0] + sr[1];
        out[(size_t)b * (E_ + 1) + E_] = sr2[0] + sr2[1];
    }
}

__global__ __launch_bounds__(256) void k_edge(
    const int* __restrict__ edges, const int* __restrict__ flag,
    const float* __restrict__ qg, const float* __restrict__ qi,
    const float* __restrict__ qj, float* __restrict__ out)
{
    int e = blockIdx.x * 256 + threadIdx.x;
    if (e >= E_) return;
    int u, v;
    if (*flag) { int4 w = ((const int4*)edges)[e]; u = w.x; v = w.z; }
    else       { int2 w = ((const int2*)edges)[e]; u = w.x; v = w.y; }
    float q0 = qg[0], q1 = qg[1], q2 = qg[2], q3 = qg[3];
    out[0 * (size_t)(E_ + 1) + e] = q0 + qi[0 * N_ + u] + qj[0 * N_ + v];
    out[1 * (size_t)(E_ + 1) + e] = q1 + qi[1 * N_ + u] + qj[1 * N_ + v];
    out[2 * (size_t)(E_ + 1) + e] = q2 + qi[2 * N_ + u] + qj[2 * N_ + v];
    out[3 * (size_t)(E_ + 1) + e] = q3 + qi[3 * N_ + u] + qj[3 * N_ + v];
}

extern "C" void kernel_launch(void* const* d_in, const int* in_sizes, int n_in,
                              void* d_out, int out_size, void* d_ws, size_t ws_size,
                              hipStream_t stream)
{
    const float* emb   = (const float*)d_in[0];
    const int*   edges = (const int*)d_in[1];
    const float* W6    = (const float*)d_in[2];
    const float* W7    = (const float*)d_in[3];
    const float* w5    = (const float*)d_in[4];
    const float* wno   = (const float*)d_in[5];
    float* out = (float*)d_out;

    float* W = (float*)d_ws;
    float* g    = W;
    float* qg   = W + 512;
    int*   flag = (int*)(W + 516);
    __hip_bfloat16* w7t = (__hip_bfloat16*)(W + 1024);
    float* qi = W + 9216;
    float* qj = W + 89216;

    hipMemsetAsync(g, 0, 512 * sizeof(float), stream);
    hipLaunchKernelGGL(k_prep, dim3(65), dim3(256), 0, stream,
                       W7, w7t, (const unsigned*)edges, flag);
    hipLaunchKernelGGL(k_main, dim3((N_ + 127) / 128, B_), dim3(256), 0, stream,
                       emb, w7t, w5, g, qi, qj);
    hipLaunchKernelGGL(k_qg, dim3(B_), dim3(128), 0, stream, g, W6, w5, wno, qg, out);
    hipLaunchKernelGGL(k_edge, dim3((E_ + 255) / 256), dim3(256), 0, stream,
                       edges, flag, qg, qi, qj, out);
}